// Round 1
// baseline (306.635 us; speedup 1.0000x reference)
//
#include <hip/hip_runtime.h>
#include <math.h>

// Problem constants (from reference)
constexpr int T_ = 131072;
constexpr int E_ = 512;
constexpr int H_ = 512;
constexpr int K_ = 1024;
constexpr int L_ = 128;

// Workspace layout (element offsets; floats unless noted)
constexpr size_t OFF_V     = 0;                    // 512 f
constexpr size_t OFF_ALPHA = 512;                  // 131072 f
constexpr size_t OFF_HIST1 = OFF_ALPHA + T_;       // 65536 u32
constexpr size_t OFF_HIST2 = OFF_HIST1 + 65536;    // 65536 u32
constexpr size_t OFF_CNT   = OFF_HIST2 + 65536;    // 2 u32 (select counters)
constexpr size_t OFF_INFO  = OFF_CNT + 2;          // 8 u32: b1, above1, thr, cnt_greater, tie_take
constexpr size_t OFF_VALS  = OFF_INFO + 8;         // 1024 f
constexpr size_t OFF_IDX   = OFF_VALS + K_;        // 1024 i32
constexpr size_t OFF_A     = OFF_IDX + K_;         // 1024 f (softmax weights)
constexpr size_t OFF_PART  = OFF_A + K_;           // 16*512 f (attn partials)
constexpr size_t OFF_GI    = OFF_PART + 16 * E_;   // 1536 f
constexpr size_t OFF_GH    = OFF_GI + 3 * H_;      // 1536 f

// Output layout: score(1) | h_new(512) | vs_new((T+1)*512) | hs_new((T+1)*512)
constexpr size_t OUT_VS = 513;
constexpr size_t OUT_HS = 513 + (size_t)(T_ + 1) * E_;

__device__ __forceinline__ unsigned fkey(float f) {
    unsigned u = __float_as_uint(f);
    return (u & 0x80000000u) ? ~u : (u | 0x80000000u);  // ascending key == ascending float
}

// Block gridDim-1: compute v = mean(emb[topic]) and write ws.v + vs_new last row.
// Other blocks: zero hist1+hist2+counters (contiguous, zero_n u32).
__global__ __launch_bounds__(512) void k_init(const int* __restrict__ topic,
                                              const float* __restrict__ emb,
                                              float* __restrict__ ws_v,
                                              unsigned* __restrict__ zero_base, int zero_n,
                                              float* __restrict__ out) {
    if (blockIdx.x == gridDim.x - 1) {
        int e = threadIdx.x;  // 512 threads, one per dim
        float s = 0.f;
        #pragma unroll 4
        for (int l = 0; l < L_; ++l) {
            int t = topic[l];
            s += emb[(size_t)t * E_ + e];
        }
        float v = s * (1.0f / L_);
        ws_v[e] = v;
        out[OUT_VS + (size_t)T_ * E_ + e] = v;  // vs_new last row
    } else {
        int i = blockIdx.x * blockDim.x + threadIdx.x;
        if (i < zero_n) zero_base[i] = 0u;
    }
}

// Mega kernel: fused {vs copy + alpha dot + hist1} and {hs copy}.
// 4 waves/block, one row per wave. Blocks [0,T/4) handle vs, [T/4,2T/4) handle hs.
__global__ __launch_bounds__(256) void k_mega(const float* __restrict__ vs,
                                              const float* __restrict__ hs,
                                              const float* __restrict__ ws_v,
                                              float* __restrict__ alpha,
                                              unsigned* __restrict__ hist1,
                                              float* __restrict__ out) {
    int wave = threadIdx.x >> 6, lane = threadIdx.x & 63;
    int b = blockIdx.x;
    bool is_vs = b < (T_ / 4);
    int row = (is_vs ? b : b - T_ / 4) * 4 + wave;
    const float* src = (is_vs ? vs : hs) + (size_t)row * E_;
    float* dst = out + (is_vs ? OUT_VS : OUT_HS) + (size_t)row * E_;
    if (is_vs) {
        float dot = 0.f;
        #pragma unroll
        for (int j = 0; j < 8; ++j) {
            int c = lane + j * 64;           // coalesced dwords (out rows only 4B-aligned)
            float x = src[c];
            dot = fmaf(x, ws_v[c], dot);
            dst[c] = x;
        }
        #pragma unroll
        for (int m = 32; m; m >>= 1) dot += __shfl_xor(dot, m, 64);
        if (lane == 0) {
            alpha[row] = dot;
            atomicAdd(&hist1[fkey(dot) >> 16], 1u);
        }
    } else {
        #pragma unroll
        for (int j = 0; j < 8; ++j) {
            int c = lane + j * 64;
            dst[c] = src[c];
        }
    }
}

// Descending scan of a 65536-bin histogram to locate the bin containing the
// Kwant-th largest. pass 0: Kwant=K -> info[0]=bin, info[1]=count_above.
// pass 1: Kwant=K-info[1] -> info[2]=thr_key, info[3]=count_greater, info[4]=tie_take.
__global__ __launch_bounds__(256) void k_scan(const unsigned* __restrict__ hist,
                                              unsigned* __restrict__ info, int pass) {
    __shared__ unsigned sS[256];
    int t = threadIdx.x;
    unsigned Kwant = (pass == 0) ? (unsigned)K_ : ((unsigned)K_ - info[1]);
    unsigned base = 65536u - (unsigned)(t + 1) * 256u;  // chunk t = descending bins
    unsigned s = 0;
    for (int j = 0; j < 256; ++j) s += hist[base + j];
    sS[t] = s;
    __syncthreads();
    unsigned C = 0;
    for (int u = 0; u < t; ++u) C += sS[u];  // exclusive prefix in descending order
    if (C < Kwant && C + sS[t] >= Kwant) {
        unsigned acc = C, bin = 0, cnt_above = 0;
        for (int j = 0; j < 256; ++j) {
            unsigned bb = 65535u - (unsigned)t * 256u - (unsigned)j;
            unsigned h = hist[bb];
            if (acc + h >= Kwant) { bin = bb; cnt_above = acc; break; }
            acc += h;
        }
        if (pass == 0) {
            info[0] = bin;
            info[1] = cnt_above;
        } else {
            unsigned thr = (info[0] << 16) | bin;
            unsigned cg = info[1] + cnt_above;
            info[2] = thr;
            info[3] = cg;
            info[4] = (unsigned)K_ - cg;
        }
    }
}

__global__ __launch_bounds__(256) void k_hist2(const float* __restrict__ alpha,
                                               const unsigned* __restrict__ info,
                                               unsigned* __restrict__ hist2) {
    int i = blockIdx.x * blockDim.x + threadIdx.x;
    unsigned key = fkey(alpha[i]);
    if ((key >> 16) == info[0]) atomicAdd(&hist2[key & 0xFFFFu], 1u);
}

__global__ __launch_bounds__(256) void k_select(const float* __restrict__ alpha,
                                                const unsigned* __restrict__ info,
                                                unsigned* __restrict__ cnt,
                                                float* __restrict__ vals,
                                                int* __restrict__ idx) {
    int i = blockIdx.x * blockDim.x + threadIdx.x;
    float a = alpha[i];
    unsigned key = fkey(a);
    unsigned thr = info[2];
    if (key > thr) {
        unsigned p = atomicAdd(&cnt[0], 1u);
        vals[p] = a; idx[p] = i;
    } else if (key == thr) {
        unsigned t = atomicAdd(&cnt[1], 1u);
        if (t < info[4]) {
            unsigned p = info[3] + t;
            vals[p] = a; idx[p] = i;
        }
    }
}

__global__ __launch_bounds__(1024) void k_softmax(const float* __restrict__ vals,
                                                  float* __restrict__ a) {
    __shared__ float red[1024];
    int t = threadIdx.x;
    float v = vals[t];
    red[t] = v;
    __syncthreads();
    for (int s = 512; s > 0; s >>= 1) { if (t < s) red[t] = fmaxf(red[t], red[t + s]); __syncthreads(); }
    float m = red[0];
    __syncthreads();
    float e = expf(v - m);
    red[t] = e;
    __syncthreads();
    for (int s = 512; s > 0; s >>= 1) { if (t < s) red[t] += red[t + s]; __syncthreads(); }
    a[t] = e / red[0];
}

// 16 blocks x 512 threads; block j sums its 64 rows into part[j] (deterministic).
__global__ __launch_bounds__(512) void k_attn(const float* __restrict__ hs,
                                              const float* __restrict__ a,
                                              const int* __restrict__ idx,
                                              float* __restrict__ part) {
    int e = threadIdx.x, j = blockIdx.x;
    float acc = 0.f;
    for (int k = j * 64; k < j * 64 + 64; ++k) {
        acc = fmaf(a[k], hs[(size_t)idx[k] * E_ + e], acc);
    }
    part[(size_t)j * E_ + e] = acc;
}

// One wave per gate-row: gi = w_ih@x + b_ih, gh = w_hh@h + b_hh.
__global__ __launch_bounds__(256) void k_gru(const float* __restrict__ wih,
                                             const float* __restrict__ whh,
                                             const float* __restrict__ bih,
                                             const float* __restrict__ bhh,
                                             const float* __restrict__ ws_v,
                                             const float* __restrict__ score_s,
                                             const float* __restrict__ h_in,
                                             float* __restrict__ gi,
                                             float* __restrict__ gh) {
    __shared__ float x[1025 + 512];
    int t = threadIdx.x;
    float ss = score_s[0];
    float pos = ss >= 0.5f ? 1.f : 0.f;
    for (int c = t; c < 1025; c += 256) {
        float xv;
        if (c < 512)       xv = ws_v[c] * pos;
        else if (c < 1024) xv = ws_v[c - 512] * (1.f - pos);
        else               xv = ss;
        x[c] = xv;
    }
    for (int c = t; c < 512; c += 256) x[1025 + c] = h_in[c];
    __syncthreads();
    int wave = t >> 6, lane = t & 63;
    int row = blockIdx.x * 4 + wave;
    const float* wr = wih + (size_t)row * 1025;
    float s1 = 0.f;
    for (int c = lane; c < 1025; c += 64) s1 = fmaf(wr[c], x[c], s1);
    const float* hr = whh + (size_t)row * 512;
    float s2 = 0.f;
    #pragma unroll
    for (int c = lane; c < 512; c += 64) s2 = fmaf(hr[c], x[1025 + c], s2);
    #pragma unroll
    for (int m = 32; m; m >>= 1) {
        s1 += __shfl_xor(s1, m, 64);
        s2 += __shfl_xor(s2, m, 64);
    }
    if (lane == 0) { gi[row] = s1 + bih[row]; gh[row] = s2 + bhh[row]; }
}

__global__ __launch_bounds__(512) void k_gru_final(const float* __restrict__ gi,
                                                   const float* __restrict__ gh,
                                                   const float* __restrict__ h_in,
                                                   float* __restrict__ out) {
    int j = threadIdx.x;
    float r = 1.f / (1.f + expf(-(gi[j] + gh[j])));
    float z = 1.f / (1.f + expf(-(gi[H_ + j] + gh[H_ + j])));
    float n = tanhf(gi[2 * H_ + j] + r * gh[2 * H_ + j]);
    float hp = h_in[j];
    float hn = (1.f - z) * n + z * hp;
    out[1 + j] = hn;                          // h_new
    out[OUT_HS + (size_t)T_ * E_ + j] = hn;   // hs_new last row
}

// Reduce attn partials, then score = [v, attn_h, h, 1024] . w_score + b_score.
__global__ __launch_bounds__(512) void k_score(const float* __restrict__ part,
                                               const float* __restrict__ ws_v,
                                               const float* __restrict__ h_in,
                                               const float* __restrict__ w_score,
                                               const float* __restrict__ b_score,
                                               float* __restrict__ out) {
    __shared__ float red[512];
    int t = threadIdx.x;
    float attn = 0.f;
    #pragma unroll
    for (int j = 0; j < 16; ++j) attn += part[(size_t)j * E_ + t];
    float d = ws_v[t] * w_score[t] + attn * w_score[512 + t] + h_in[t] * w_score[1024 + t];
    if (t == 0) d += 1024.0f * w_score[1536] + b_score[0];
    red[t] = d;
    __syncthreads();
    for (int s = 256; s > 0; s >>= 1) { if (t < s) red[t] += red[t + s]; __syncthreads(); }
    if (t == 0) out[0] = red[0];
}

extern "C" void kernel_launch(void* const* d_in, const int* in_sizes, int n_in,
                              void* d_out, int out_size, void* d_ws, size_t ws_size,
                              hipStream_t stream) {
    const int*   topic   = (const int*)d_in[0];
    const float* score_s = (const float*)d_in[1];
    const float* emb     = (const float*)d_in[2];
    const float* h_in    = (const float*)d_in[3];
    const float* vs      = (const float*)d_in[4];
    const float* hs      = (const float*)d_in[5];
    const float* w_ih    = (const float*)d_in[6];
    const float* w_hh    = (const float*)d_in[7];
    const float* b_ih    = (const float*)d_in[8];
    const float* b_hh    = (const float*)d_in[9];
    const float* w_score = (const float*)d_in[10];
    const float* b_score = (const float*)d_in[11];
    float* out = (float*)d_out;

    float*    wsf   = (float*)d_ws;
    float*    v_ws  = wsf + OFF_V;
    float*    alpha = wsf + OFF_ALPHA;
    unsigned* hist1 = (unsigned*)(wsf + OFF_HIST1);
    unsigned* hist2 = (unsigned*)(wsf + OFF_HIST2);
    unsigned* cnt   = (unsigned*)(wsf + OFF_CNT);
    unsigned* info  = (unsigned*)(wsf + OFF_INFO);
    float*    vals  = wsf + OFF_VALS;
    int*      idx   = (int*)(wsf + OFF_IDX);
    float*    aw    = wsf + OFF_A;
    float*    part  = wsf + OFF_PART;
    float*    gi    = wsf + OFF_GI;
    float*    gh    = wsf + OFF_GH;

    const int zero_n = 65536 + 65536 + 2;  // hist1 + hist2 + cnt (contiguous)

    // 1) v + zero-init (zeroing must precede hist use; v must precede k_mega)
    hipLaunchKernelGGL(k_init, dim3(258), dim3(512), 0, stream,
                       topic, emb, v_ws, hist1, zero_n, out);
    // 2) fused copies + alpha + hist1
    hipLaunchKernelGGL(k_mega, dim3(2 * (T_ / 4)), dim3(256), 0, stream,
                       vs, hs, v_ws, alpha, hist1, out);
    // 3-6) exact radix-select of top-K
    hipLaunchKernelGGL(k_scan, dim3(1), dim3(256), 0, stream, hist1, info, 0);
    hipLaunchKernelGGL(k_hist2, dim3(T_ / 256), dim3(256), 0, stream, alpha, info, hist2);
    hipLaunchKernelGGL(k_scan, dim3(1), dim3(256), 0, stream, hist2, info, 1);
    hipLaunchKernelGGL(k_select, dim3(T_ / 256), dim3(256), 0, stream, alpha, info, cnt, vals, idx);
    // 7-8) softmax + attention gather (deterministic partials)
    hipLaunchKernelGGL(k_softmax, dim3(1), dim3(1024), 0, stream, vals, aw);
    hipLaunchKernelGGL(k_attn, dim3(16), dim3(512), 0, stream, hs, aw, idx, part);
    // 9-10) GRU (independent of attention path)
    hipLaunchKernelGGL(k_gru, dim3(384), dim3(256), 0, stream,
                       w_ih, w_hh, b_ih, b_hh, v_ws, score_s, h_in, gi, gh);
    hipLaunchKernelGGL(k_gru_final, dim3(1), dim3(512), 0, stream, gi, gh, h_in, out);
    // 11) score
    hipLaunchKernelGGL(k_score, dim3(1), dim3(512), 0, stream,
                       part, v_ws, h_in, w_score, b_score, out);
}

// Round 2
// 295.981 us; speedup vs baseline: 1.0360x; 1.0360x over previous
//
#include <hip/hip_runtime.h>
#include <math.h>

// Problem constants (from reference)
constexpr int T_ = 131072;
constexpr int E_ = 512;
constexpr int H_ = 512;
constexpr int K_ = 1024;
constexpr int L_ = 128;

// Workspace layout (element offsets; floats unless noted)
constexpr size_t OFF_V     = 0;                    // 512 f
constexpr size_t OFF_ALPHA = 512;                  // 131072 f
constexpr size_t OFF_HIST1 = OFF_ALPHA + T_;       // 65536 u32
constexpr size_t OFF_HIST2 = OFF_HIST1 + 65536;    // 65536 u32
constexpr size_t OFF_CNT   = OFF_HIST2 + 65536;    // 2 u32 (select counters)
constexpr size_t OFF_INFO  = OFF_CNT + 2;          // 8 u32
constexpr size_t OFF_VALS  = OFF_INFO + 8;         // 1024 f
constexpr size_t OFF_IDX   = OFF_VALS + K_;        // 1024 i32
constexpr size_t OFF_A     = OFF_IDX + K_;         // 1024 f (softmax weights)
constexpr size_t OFF_PART  = OFF_A + K_;           // 16*512 f (attn partials)
constexpr size_t OFF_GI    = OFF_PART + 16 * E_;   // 1536 f
constexpr size_t OFF_GH    = OFF_GI + 3 * H_;      // 1536 f

// Output layout: score(1) | h_new(512) | vs_new((T+1)*512) | hs_new((T+1)*512)
constexpr size_t OUT_VS = 513;
constexpr size_t OUT_HS = 513 + (size_t)(T_ + 1) * E_;

__device__ __forceinline__ unsigned fkey(float f) {
    unsigned u = __float_as_uint(f);
    return (u & 0x80000000u) ? ~u : (u | 0x80000000u);  // ascending key == ascending float
}

// Block gridDim-1: compute v = mean(emb[topic]); two 512-thread halves each sum
// 64 topics (fixed order -> deterministic), combine in LDS.
// Other blocks: zero hist1+hist2+counters (contiguous, zero_n u32).
__global__ __launch_bounds__(1024) void k_init(const int* __restrict__ topic,
                                               const float* __restrict__ emb,
                                               float* __restrict__ ws_v,
                                               unsigned* __restrict__ zero_base, int zero_n,
                                               float* __restrict__ out) {
    if (blockIdx.x == gridDim.x - 1) {
        __shared__ float part[512];
        int t = threadIdx.x;
        int e = t & 511, g = t >> 9;       // g in {0,1}
        float s = 0.f;
        #pragma unroll 8
        for (int l = g * 64; l < g * 64 + 64; ++l) {
            int tp = topic[l];
            s += emb[(size_t)tp * E_ + e];
        }
        if (g == 1) part[e] = s;
        __syncthreads();
        if (g == 0) {
            float v = (s + part[e]) * (1.0f / L_);
            ws_v[e] = v;
            out[OUT_VS + (size_t)T_ * E_ + e] = v;  // vs_new last row
        }
    } else {
        int i = blockIdx.x * blockDim.x + threadIdx.x;
        if (i < zero_n) zero_base[i] = 0u;
    }
}

// Mega kernel: fused {vs copy + alpha dot + hist1} and {hs copy}.
// 4 waves/block, one 512-elem row per wave. Blocks [0,T/4): vs, [T/4,2T/4): hs.
// Loads: aligned float4. Stores: output rows start at element 513+512*row
// (4B-aligned only) -> restage row via LDS, emit aligned float4 at dst+3
// (element 516+512*row, 16B-aligned) + 4 scalar head/tail dwords.
__global__ __launch_bounds__(256) void k_mega(const float* __restrict__ vs,
                                              const float* __restrict__ hs,
                                              const float* __restrict__ ws_v,
                                              float* __restrict__ alpha,
                                              unsigned* __restrict__ hist1,
                                              float* __restrict__ out) {
    __shared__ float lds[4][512];
    int wave = threadIdx.x >> 6, lane = threadIdx.x & 63;
    int b = blockIdx.x;
    bool is_vs = b < (T_ / 4);
    int row = (is_vs ? b : b - T_ / 4) * 4 + wave;
    const float4* src4 = (const float4*)((is_vs ? vs : hs) + (size_t)row * E_);
    float4 a0 = src4[lane];
    float4 a1 = src4[lane + 64];
    if (is_vs) {
        const float4* v4 = (const float4*)ws_v;
        float4 b0 = v4[lane];
        float4 b1 = v4[lane + 64];
        float dot = 0.f;
        dot = fmaf(a0.x, b0.x, dot); dot = fmaf(a0.y, b0.y, dot);
        dot = fmaf(a0.z, b0.z, dot); dot = fmaf(a0.w, b0.w, dot);
        dot = fmaf(a1.x, b1.x, dot); dot = fmaf(a1.y, b1.y, dot);
        dot = fmaf(a1.z, b1.z, dot); dot = fmaf(a1.w, b1.w, dot);
        #pragma unroll
        for (int m = 32; m; m >>= 1) dot += __shfl_xor(dot, m, 64);
        if (lane == 0) {
            alpha[row] = dot;
            atomicAdd(&hist1[fkey(dot) >> 16], 1u);
        }
    }
    float* l = lds[wave];
    ((float4*)l)[lane] = a0;
    ((float4*)l)[lane + 64] = a1;
    __syncthreads();
    float* dst = out + (is_vs ? OUT_VS : OUT_HS) + (size_t)row * E_;
    if (lane < 3) dst[lane] = l[lane];          // head: c = 0,1,2
    if (lane == 63) dst[511] = l[511];          // tail: c = 511
    float4* d4 = (float4*)(dst + 3);            // 16B-aligned
    {
        int i = lane;                            // i in [0,64)
        float4 s;
        s.x = l[3 + 4 * i]; s.y = l[4 + 4 * i];
        s.z = l[5 + 4 * i]; s.w = l[6 + 4 * i];
        d4[i] = s;
    }
    {
        int i = lane + 64;                       // i in [64,127)
        if (i < 127) {
            float4 s;
            s.x = l[3 + 4 * i]; s.y = l[4 + 4 * i];
            s.z = l[5 + 4 * i]; s.w = l[6 + 4 * i];
            d4[i] = s;
        }
    }
}

// Descending scan of a 65536-bin histogram (unchanged, verified round 1).
__global__ __launch_bounds__(256) void k_scan(const unsigned* __restrict__ hist,
                                              unsigned* __restrict__ info, int pass) {
    __shared__ unsigned sS[256];
    int t = threadIdx.x;
    unsigned Kwant = (pass == 0) ? (unsigned)K_ : ((unsigned)K_ - info[1]);
    unsigned base = 65536u - (unsigned)(t + 1) * 256u;
    unsigned s = 0;
    for (int j = 0; j < 256; ++j) s += hist[base + j];
    sS[t] = s;
    __syncthreads();
    unsigned C = 0;
    for (int u = 0; u < t; ++u) C += sS[u];
    if (C < Kwant && C + sS[t] >= Kwant) {
        unsigned acc = C, bin = 0, cnt_above = 0;
        for (int j = 0; j < 256; ++j) {
            unsigned bb = 65535u - (unsigned)t * 256u - (unsigned)j;
            unsigned h = hist[bb];
            if (acc + h >= Kwant) { bin = bb; cnt_above = acc; break; }
            acc += h;
        }
        if (pass == 0) {
            info[0] = bin;
            info[1] = cnt_above;
        } else {
            unsigned thr = (info[0] << 16) | bin;
            unsigned cg = info[1] + cnt_above;
            info[2] = thr;
            info[3] = cg;
            info[4] = (unsigned)K_ - cg;
        }
    }
}

__global__ __launch_bounds__(256) void k_hist2(const float* __restrict__ alpha,
                                               const unsigned* __restrict__ info,
                                               unsigned* __restrict__ hist2) {
    int i = blockIdx.x * blockDim.x + threadIdx.x;
    unsigned key = fkey(alpha[i]);
    if ((key >> 16) == info[0]) atomicAdd(&hist2[key & 0xFFFFu], 1u);
}

__global__ __launch_bounds__(256) void k_select(const float* __restrict__ alpha,
                                                const unsigned* __restrict__ info,
                                                unsigned* __restrict__ cnt,
                                                float* __restrict__ vals,
                                                int* __restrict__ idx) {
    int i = blockIdx.x * blockDim.x + threadIdx.x;
    float a = alpha[i];
    unsigned key = fkey(a);
    unsigned thr = info[2];
    if (key > thr) {
        unsigned p = atomicAdd(&cnt[0], 1u);
        vals[p] = a; idx[p] = i;
    } else if (key == thr) {
        unsigned t = atomicAdd(&cnt[1], 1u);
        if (t < info[4]) {
            unsigned p = info[3] + t;
            vals[p] = a; idx[p] = i;
        }
    }
}

__global__ __launch_bounds__(1024) void k_softmax(const float* __restrict__ vals,
                                                  float* __restrict__ a) {
    __shared__ float red[1024];
    int t = threadIdx.x;
    float v = vals[t];
    red[t] = v;
    __syncthreads();
    for (int s = 512; s > 0; s >>= 1) { if (t < s) red[t] = fmaxf(red[t], red[t + s]); __syncthreads(); }
    float m = red[0];
    __syncthreads();
    float e = expf(v - m);
    red[t] = e;
    __syncthreads();
    for (int s = 512; s > 0; s >>= 1) { if (t < s) red[t] += red[t + s]; __syncthreads(); }
    a[t] = e / red[0];
}

// 16 blocks x 512 threads; block j sums its 64 rows into part[j] (deterministic).
__global__ __launch_bounds__(512) void k_attn(const float* __restrict__ hs,
                                              const float* __restrict__ a,
                                              const int* __restrict__ idx,
                                              float* __restrict__ part) {
    int e = threadIdx.x, j = blockIdx.x;
    float acc = 0.f;
    for (int k = j * 64; k < j * 64 + 64; ++k) {
        acc = fmaf(a[k], hs[(size_t)idx[k] * E_ + e], acc);
    }
    part[(size_t)j * E_ + e] = acc;
}

// One wave per gate-row: gi = w_ih@x + b_ih, gh = w_hh@h + b_hh.
__global__ __launch_bounds__(256) void k_gru(const float* __restrict__ wih,
                                             const float* __restrict__ whh,
                                             const float* __restrict__ bih,
                                             const float* __restrict__ bhh,
                                             const float* __restrict__ ws_v,
                                             const float* __restrict__ score_s,
                                             const float* __restrict__ h_in,
                                             float* __restrict__ gi,
                                             float* __restrict__ gh) {
    __shared__ float x[1025 + 512];
    int t = threadIdx.x;
    float ss = score_s[0];
    float pos = ss >= 0.5f ? 1.f : 0.f;
    for (int c = t; c < 1025; c += 256) {
        float xv;
        if (c < 512)       xv = ws_v[c] * pos;
        else if (c < 1024) xv = ws_v[c - 512] * (1.f - pos);
        else               xv = ss;
        x[c] = xv;
    }
    for (int c = t; c < 512; c += 256) x[1025 + c] = h_in[c];
    __syncthreads();
    int wave = t >> 6, lane = t & 63;
    int row = blockIdx.x * 4 + wave;
    const float* wr = wih + (size_t)row * 1025;
    float s1 = 0.f;
    for (int c = lane; c < 1025; c += 64) s1 = fmaf(wr[c], x[c], s1);
    const float* hr = whh + (size_t)row * 512;
    float s2 = 0.f;
    #pragma unroll
    for (int c = lane; c < 512; c += 64) s2 = fmaf(hr[c], x[1025 + c], s2);
    #pragma unroll
    for (int m = 32; m; m >>= 1) {
        s1 += __shfl_xor(s1, m, 64);
        s2 += __shfl_xor(s2, m, 64);
    }
    if (lane == 0) { gi[row] = s1 + bih[row]; gh[row] = s2 + bhh[row]; }
}

// Fused GRU-finalize + score (independent outputs; one 512-thread block).
__global__ __launch_bounds__(512) void k_final(const float* __restrict__ gi,
                                               const float* __restrict__ gh,
                                               const float* __restrict__ h_in,
                                               const float* __restrict__ part,
                                               const float* __restrict__ ws_v,
                                               const float* __restrict__ w_score,
                                               const float* __restrict__ b_score,
                                               float* __restrict__ out) {
    __shared__ float red[512];
    int j = threadIdx.x;
    // GRU finalize
    float r = 1.f / (1.f + expf(-(gi[j] + gh[j])));
    float z = 1.f / (1.f + expf(-(gi[H_ + j] + gh[H_ + j])));
    float n = tanhf(gi[2 * H_ + j] + r * gh[2 * H_ + j]);
    float hp = h_in[j];
    float hn = (1.f - z) * n + z * hp;
    out[1 + j] = hn;                          // h_new
    out[OUT_HS + (size_t)T_ * E_ + j] = hn;   // hs_new last row
    // Score
    float attn = 0.f;
    #pragma unroll
    for (int jj = 0; jj < 16; ++jj) attn += part[(size_t)jj * E_ + j];
    float d = ws_v[j] * w_score[j] + attn * w_score[512 + j] + hp * w_score[1024 + j];
    if (j == 0) d += 1024.0f * w_score[1536] + b_score[0];
    red[j] = d;
    __syncthreads();
    for (int s = 256; s > 0; s >>= 1) { if (j < s) red[j] += red[j + s]; __syncthreads(); }
    if (j == 0) out[0] = red[0];
}

extern "C" void kernel_launch(void* const* d_in, const int* in_sizes, int n_in,
                              void* d_out, int out_size, void* d_ws, size_t ws_size,
                              hipStream_t stream) {
    const int*   topic   = (const int*)d_in[0];
    const float* score_s = (const float*)d_in[1];
    const float* emb     = (const float*)d_in[2];
    const float* h_in    = (const float*)d_in[3];
    const float* vs      = (const float*)d_in[4];
    const float* hs      = (const float*)d_in[5];
    const float* w_ih    = (const float*)d_in[6];
    const float* w_hh    = (const float*)d_in[7];
    const float* b_ih    = (const float*)d_in[8];
    const float* b_hh    = (const float*)d_in[9];
    const float* w_score = (const float*)d_in[10];
    const float* b_score = (const float*)d_in[11];
    float* out = (float*)d_out;

    float*    wsf   = (float*)d_ws;
    float*    v_ws  = wsf + OFF_V;
    float*    alpha = wsf + OFF_ALPHA;
    unsigned* hist1 = (unsigned*)(wsf + OFF_HIST1);
    unsigned* hist2 = (unsigned*)(wsf + OFF_HIST2);
    unsigned* cnt   = (unsigned*)(wsf + OFF_CNT);
    unsigned* info  = (unsigned*)(wsf + OFF_INFO);
    float*    vals  = wsf + OFF_VALS;
    int*      idx   = (int*)(wsf + OFF_IDX);
    float*    aw    = wsf + OFF_A;
    float*    part  = wsf + OFF_PART;
    float*    gi    = wsf + OFF_GI;
    float*    gh    = wsf + OFF_GH;

    const int zero_n = 65536 + 65536 + 2;  // hist1 + hist2 + cnt (contiguous)

    // 1) v + zero-init
    hipLaunchKernelGGL(k_init, dim3(130), dim3(1024), 0, stream,
                       topic, emb, v_ws, hist1, zero_n, out);
    // 2) fused copies + alpha + hist1 (vectorized)
    hipLaunchKernelGGL(k_mega, dim3(2 * (T_ / 4)), dim3(256), 0, stream,
                       vs, hs, v_ws, alpha, hist1, out);
    // 3-6) exact radix-select of top-K
    hipLaunchKernelGGL(k_scan, dim3(1), dim3(256), 0, stream, hist1, info, 0);
    hipLaunchKernelGGL(k_hist2, dim3(T_ / 256), dim3(256), 0, stream, alpha, info, hist2);
    hipLaunchKernelGGL(k_scan, dim3(1), dim3(256), 0, stream, hist2, info, 1);
    hipLaunchKernelGGL(k_select, dim3(T_ / 256), dim3(256), 0, stream, alpha, info, cnt, vals, idx);
    // 7-8) softmax + attention gather
    hipLaunchKernelGGL(k_softmax, dim3(1), dim3(1024), 0, stream, vals, aw);
    hipLaunchKernelGGL(k_attn, dim3(16), dim3(512), 0, stream, hs, aw, idx, part);
    // 9) GRU gates
    hipLaunchKernelGGL(k_gru, dim3(384), dim3(256), 0, stream,
                       w_ih, w_hh, b_ih, b_hh, v_ws, score_s, h_in, gi, gh);
    // 10) fused GRU-finalize + score
    hipLaunchKernelGGL(k_final, dim3(1), dim3(512), 0, stream,
                       gi, gh, h_in, part, v_ws, w_score, b_score, out);
}

// Round 3
// 274.725 us; speedup vs baseline: 1.1162x; 1.0774x over previous
//
#include <hip/hip_runtime.h>
#include <math.h>

// Problem constants (from reference)
constexpr int T_ = 131072;
constexpr int E_ = 512;
constexpr int H_ = 512;
constexpr int K_ = 1024;
constexpr int L_ = 128;

typedef __attribute__((ext_vector_type(4))) float f32x4;

// Workspace layout (element offsets; floats unless noted)
constexpr size_t OFF_V     = 0;                    // 512 f
constexpr size_t OFF_ALPHA = 512;                  // 131072 f
constexpr size_t OFF_HIST1 = OFF_ALPHA + T_;       // 65536 u32
constexpr size_t OFF_HIST2 = OFF_HIST1 + 65536;    // 65536 u32 (reused as attn partials later)
constexpr size_t OFF_CNT   = OFF_HIST2 + 65536;    // 2 u32 (select counters)
constexpr size_t OFF_INFO  = OFF_CNT + 2;          // 8 u32
constexpr size_t OFF_VALS  = OFF_INFO + 8;         // 1024 f
constexpr size_t OFF_IDX   = OFF_VALS + K_;        // 1024 i32
constexpr size_t OFF_GI    = OFF_IDX + K_;         // 1536 f
constexpr size_t OFF_GH    = OFF_GI + 3 * H_;      // 1536 f

// Output layout: score(1) | h_new(512) | vs_new((T+1)*512) | hs_new((T+1)*512)
constexpr size_t OUT_VS = 513;
constexpr size_t OUT_HS = 513 + (size_t)(T_ + 1) * E_;

__device__ __forceinline__ unsigned fkey(float f) {
    unsigned u = __float_as_uint(f);
    return (u & 0x80000000u) ? ~u : (u | 0x80000000u);  // ascending key == ascending float
}

// Block gridDim-1: compute v = mean(emb[topic]); two 512-thread halves each sum
// 64 topics (fixed order -> deterministic), combine in LDS.
// Other blocks: zero hist1+hist2+counters (contiguous, zero_n u32).
__global__ __launch_bounds__(1024) void k_init(const int* __restrict__ topic,
                                               const float* __restrict__ emb,
                                               float* __restrict__ ws_v,
                                               unsigned* __restrict__ zero_base, int zero_n,
                                               float* __restrict__ out) {
    if (blockIdx.x == gridDim.x - 1) {
        __shared__ float part[512];
        int t = threadIdx.x;
        int e = t & 511, g = t >> 9;       // g in {0,1}
        float s = 0.f;
        #pragma unroll 8
        for (int l = g * 64; l < g * 64 + 64; ++l) {
            int tp = topic[l];
            s += emb[(size_t)tp * E_ + e];
        }
        if (g == 1) part[e] = s;
        __syncthreads();
        if (g == 0) {
            float v = (s + part[e]) * (1.0f / L_);
            ws_v[e] = v;
            out[OUT_VS + (size_t)T_ * E_ + e] = v;  // vs_new last row
        }
    } else {
        int i = blockIdx.x * blockDim.x + threadIdx.x;
        if (i < zero_n) zero_base[i] = 0u;
    }
}

// Mega kernel: fused {vs copy + alpha dot + hist1} and {hs copy}.
// 4 waves/block, one 512-elem row per wave. Blocks [0,T/4): vs, [T/4,2T/4): hs.
// Nontemporal float4 loads/stores (1 GB single-use stream -> don't thrash L2).
// Output rows start at element 513+512*row (4B-aligned); realign to 16B via
// shuffle-rotate: d4[i] = (e[4i+3], e[4i+4..6]) = (own a.w, next lane's a.xyz).
// No LDS, no __syncthreads.
__global__ __launch_bounds__(256) void k_mega(const float* __restrict__ vs,
                                              const float* __restrict__ hs,
                                              const float* __restrict__ ws_v,
                                              float* __restrict__ alpha,
                                              unsigned* __restrict__ hist1,
                                              float* __restrict__ out) {
    int wave = threadIdx.x >> 6, lane = threadIdx.x & 63;
    int b = blockIdx.x;
    bool is_vs = b < (T_ / 4);
    int row = (is_vs ? b : b - T_ / 4) * 4 + wave;
    const f32x4* src4 = (const f32x4*)((is_vs ? vs : hs) + (size_t)row * E_);
    f32x4 a0 = __builtin_nontemporal_load(&src4[lane]);
    f32x4 a1 = __builtin_nontemporal_load(&src4[lane + 64]);
    if (is_vs) {
        const f32x4* v4 = (const f32x4*)ws_v;
        f32x4 b0 = v4[lane];
        f32x4 b1 = v4[lane + 64];
        float dot = 0.f;
        dot = fmaf(a0.x, b0.x, dot); dot = fmaf(a0.y, b0.y, dot);
        dot = fmaf(a0.z, b0.z, dot); dot = fmaf(a0.w, b0.w, dot);
        dot = fmaf(a1.x, b1.x, dot); dot = fmaf(a1.y, b1.y, dot);
        dot = fmaf(a1.z, b1.z, dot); dot = fmaf(a1.w, b1.w, dot);
        #pragma unroll
        for (int m = 32; m; m >>= 1) dot += __shfl_xor(dot, m, 64);
        if (lane == 0) {
            alpha[row] = dot;
            atomicAdd(&hist1[fkey(dot) >> 16], 1u);
        }
    }
    // Shuffle-rotate realignment
    int nl = (lane + 1) & 63;
    float n0x = __shfl(a0.x, nl, 64), n0y = __shfl(a0.y, nl, 64), n0z = __shfl(a0.z, nl, 64);
    float n1x = __shfl(a1.x, nl, 64), n1y = __shfl(a1.y, nl, 64), n1z = __shfl(a1.z, nl, 64);
    float* dst = out + (is_vs ? OUT_VS : OUT_HS) + (size_t)row * E_;
    f32x4* d4 = (f32x4*)(dst + 3);            // 16B-aligned
    bool last = (lane == 63);
    f32x4 lo;
    lo.x = a0.w;
    lo.y = last ? n1x : n0x;   // lane 63: e[256..258] = a1.xyz of lane 0
    lo.z = last ? n1y : n0y;
    lo.w = last ? n1z : n0z;
    __builtin_nontemporal_store(lo, &d4[lane]);
    if (!last) {
        f32x4 hi;
        hi.x = a1.w; hi.y = n1x; hi.z = n1y; hi.w = n1z;
        __builtin_nontemporal_store(hi, &d4[lane + 64]);
    }
    if (lane == 0) { dst[0] = a0.x; dst[1] = a0.y; dst[2] = a0.z; }
    if (last) dst[511] = a1.w;
}

// Descending scan of a 65536-bin histogram (unchanged, verified).
__global__ __launch_bounds__(256) void k_scan(const unsigned* __restrict__ hist,
                                              unsigned* __restrict__ info, int pass) {
    __shared__ unsigned sS[256];
    int t = threadIdx.x;
    unsigned Kwant = (pass == 0) ? (unsigned)K_ : ((unsigned)K_ - info[1]);
    unsigned base = 65536u - (unsigned)(t + 1) * 256u;
    unsigned s = 0;
    for (int j = 0; j < 256; ++j) s += hist[base + j];
    sS[t] = s;
    __syncthreads();
    unsigned C = 0;
    for (int u = 0; u < t; ++u) C += sS[u];
    if (C < Kwant && C + sS[t] >= Kwant) {
        unsigned acc = C, bin = 0, cnt_above = 0;
        for (int j = 0; j < 256; ++j) {
            unsigned bb = 65535u - (unsigned)t * 256u - (unsigned)j;
            unsigned h = hist[bb];
            if (acc + h >= Kwant) { bin = bb; cnt_above = acc; break; }
            acc += h;
        }
        if (pass == 0) {
            info[0] = bin;
            info[1] = cnt_above;
        } else {
            unsigned thr = (info[0] << 16) | bin;
            unsigned cg = info[1] + cnt_above;
            info[2] = thr;
            info[3] = cg;
            info[4] = (unsigned)K_ - cg;
        }
    }
}

__global__ __launch_bounds__(256) void k_hist2(const float* __restrict__ alpha,
                                               const unsigned* __restrict__ info,
                                               unsigned* __restrict__ hist2) {
    int i = blockIdx.x * blockDim.x + threadIdx.x;
    unsigned key = fkey(alpha[i]);
    if ((key >> 16) == info[0]) atomicAdd(&hist2[key & 0xFFFFu], 1u);
}

__global__ __launch_bounds__(256) void k_select(const float* __restrict__ alpha,
                                                const unsigned* __restrict__ info,
                                                unsigned* __restrict__ cnt,
                                                float* __restrict__ vals,
                                                int* __restrict__ idx) {
    int i = blockIdx.x * blockDim.x + threadIdx.x;
    float a = alpha[i];
    unsigned key = fkey(a);
    unsigned thr = info[2];
    if (key > thr) {
        unsigned p = atomicAdd(&cnt[0], 1u);
        vals[p] = a; idx[p] = i;
    } else if (key == thr) {
        unsigned t = atomicAdd(&cnt[1], 1u);
        if (t < info[4]) {
            unsigned p = info[3] + t;
            vals[p] = a; idx[p] = i;
        }
    }
}

// Fused softmax + attention gather. 64 blocks x 512 threads; each block
// redundantly computes softmax stats over the 1024 vals (L2-resident), then
// gathers its 16 rows into part[j] (deterministic fixed order).
__global__ __launch_bounds__(512) void k_attn(const float* __restrict__ hs,
                                              const float* __restrict__ vals,
                                              const int* __restrict__ idx,
                                              float* __restrict__ part) {
    __shared__ float red[512];
    int t = threadIdx.x, j = blockIdx.x;
    float v0 = vals[t], v1 = vals[t + 512];
    red[t] = fmaxf(v0, v1);
    __syncthreads();
    for (int s = 256; s > 0; s >>= 1) { if (t < s) red[t] = fmaxf(red[t], red[t + s]); __syncthreads(); }
    float m = red[0];
    __syncthreads();
    red[t] = expf(v0 - m) + expf(v1 - m);
    __syncthreads();
    for (int s = 256; s > 0; s >>= 1) { if (t < s) red[t] += red[t + s]; __syncthreads(); }
    float S = red[0];
    float acc = 0.f;
    #pragma unroll
    for (int k = j * 16; k < j * 16 + 16; ++k) {
        float w = expf(vals[k] - m) / S;
        acc = fmaf(w, hs[(size_t)idx[k] * E_ + t], acc);
    }
    part[(size_t)j * E_ + t] = acc;
}

// One wave per gate-row: gi = w_ih@x + b_ih, gh = w_hh@h + b_hh.
__global__ __launch_bounds__(256) void k_gru(const float* __restrict__ wih,
                                             const float* __restrict__ whh,
                                             const float* __restrict__ bih,
                                             const float* __restrict__ bhh,
                                             const float* __restrict__ ws_v,
                                             const float* __restrict__ score_s,
                                             const float* __restrict__ h_in,
                                             float* __restrict__ gi,
                                             float* __restrict__ gh) {
    __shared__ float x[1025 + 512];
    int t = threadIdx.x;
    float ss = score_s[0];
    float pos = ss >= 0.5f ? 1.f : 0.f;
    for (int c = t; c < 1025; c += 256) {
        float xv;
        if (c < 512)       xv = ws_v[c] * pos;
        else if (c < 1024) xv = ws_v[c - 512] * (1.f - pos);
        else               xv = ss;
        x[c] = xv;
    }
    for (int c = t; c < 512; c += 256) x[1025 + c] = h_in[c];
    __syncthreads();
    int wave = t >> 6, lane = t & 63;
    int row = blockIdx.x * 4 + wave;
    const float* wr = wih + (size_t)row * 1025;
    float s1 = 0.f;
    for (int c = lane; c < 1025; c += 64) s1 = fmaf(wr[c], x[c], s1);
    const float* hr = whh + (size_t)row * 512;
    float s2 = 0.f;
    #pragma unroll
    for (int c = lane; c < 512; c += 64) s2 = fmaf(hr[c], x[1025 + c], s2);
    #pragma unroll
    for (int m = 32; m; m >>= 1) {
        s1 += __shfl_xor(s1, m, 64);
        s2 += __shfl_xor(s2, m, 64);
    }
    if (lane == 0) { gi[row] = s1 + bih[row]; gh[row] = s2 + bhh[row]; }
}

// Fused GRU-finalize + score (one 512-thread block).
__global__ __launch_bounds__(512) void k_final(const float* __restrict__ gi,
                                               const float* __restrict__ gh,
                                               const float* __restrict__ h_in,
                                               const float* __restrict__ part,
                                               const float* __restrict__ ws_v,
                                               const float* __restrict__ w_score,
                                               const float* __restrict__ b_score,
                                               float* __restrict__ out) {
    __shared__ float red[512];
    int j = threadIdx.x;
    // GRU finalize
    float r = 1.f / (1.f + expf(-(gi[j] + gh[j])));
    float z = 1.f / (1.f + expf(-(gi[H_ + j] + gh[H_ + j])));
    float n = tanhf(gi[2 * H_ + j] + r * gh[2 * H_ + j]);
    float hp = h_in[j];
    float hn = (1.f - z) * n + z * hp;
    out[1 + j] = hn;                          // h_new
    out[OUT_HS + (size_t)T_ * E_ + j] = hn;   // hs_new last row
    // Score: reduce 64 attn partials, dot with w_score
    float attn = 0.f;
    for (int jj = 0; jj < 64; ++jj) attn += part[(size_t)jj * E_ + j];
    float d = ws_v[j] * w_score[j] + attn * w_score[512 + j] + hp * w_score[1024 + j];
    if (j == 0) d += 1024.0f * w_score[1536] + b_score[0];
    red[j] = d;
    __syncthreads();
    for (int s = 256; s > 0; s >>= 1) { if (j < s) red[j] += red[j + s]; __syncthreads(); }
    if (j == 0) out[0] = red[0];
}

extern "C" void kernel_launch(void* const* d_in, const int* in_sizes, int n_in,
                              void* d_out, int out_size, void* d_ws, size_t ws_size,
                              hipStream_t stream) {
    const int*   topic   = (const int*)d_in[0];
    const float* score_s = (const float*)d_in[1];
    const float* emb     = (const float*)d_in[2];
    const float* h_in    = (const float*)d_in[3];
    const float* vs      = (const float*)d_in[4];
    const float* hs      = (const float*)d_in[5];
    const float* w_ih    = (const float*)d_in[6];
    const float* w_hh    = (const float*)d_in[7];
    const float* b_ih    = (const float*)d_in[8];
    const float* b_hh    = (const float*)d_in[9];
    const float* w_score = (const float*)d_in[10];
    const float* b_score = (const float*)d_in[11];
    float* out = (float*)d_out;

    float*    wsf   = (float*)d_ws;
    float*    v_ws  = wsf + OFF_V;
    float*    alpha = wsf + OFF_ALPHA;
    unsigned* hist1 = (unsigned*)(wsf + OFF_HIST1);
    unsigned* hist2 = (unsigned*)(wsf + OFF_HIST2);
    unsigned* cnt   = (unsigned*)(wsf + OFF_CNT);
    unsigned* info  = (unsigned*)(wsf + OFF_INFO);
    float*    vals  = wsf + OFF_VALS;
    int*      idx   = (int*)(wsf + OFF_IDX);
    float*    part  = (float*)hist2;   // hist2 dead after scan pass1; reuse (re-zeroed next call)
    float*    gi    = wsf + OFF_GI;
    float*    gh    = wsf + OFF_GH;

    const int zero_n = 65536 + 65536 + 2;  // hist1 + hist2 + cnt (contiguous)

    // 1) v + zero-init
    hipLaunchKernelGGL(k_init, dim3(130), dim3(1024), 0, stream,
                       topic, emb, v_ws, hist1, zero_n, out);
    // 2) fused copies + alpha + hist1 (NT streams, shfl realign)
    hipLaunchKernelGGL(k_mega, dim3(2 * (T_ / 4)), dim3(256), 0, stream,
                       vs, hs, v_ws, alpha, hist1, out);
    // 3-6) exact radix-select of top-K
    hipLaunchKernelGGL(k_scan, dim3(1), dim3(256), 0, stream, hist1, info, 0);
    hipLaunchKernelGGL(k_hist2, dim3(T_ / 256), dim3(256), 0, stream, alpha, info, hist2);
    hipLaunchKernelGGL(k_scan, dim3(1), dim3(256), 0, stream, hist2, info, 1);
    hipLaunchKernelGGL(k_select, dim3(T_ / 256), dim3(256), 0, stream, alpha, info, cnt, vals, idx);
    // 7) fused softmax + attention gather (partials into dead hist2 region)
    hipLaunchKernelGGL(k_attn, dim3(64), dim3(512), 0, stream, hs, vals, idx, part);
    // 8) GRU gates
    hipLaunchKernelGGL(k_gru, dim3(384), dim3(256), 0, stream,
                       w_ih, w_hh, b_ih, b_hh, v_ws, score_s, h_in, gi, gh);
    // 9) fused GRU-finalize + score
    hipLaunchKernelGGL(k_final, dim3(1), dim3(512), 0, stream,
                       gi, gh, h_in, part, v_ws, w_score, b_score, out);
}